// Round 6
// baseline (393.216 us; speedup 1.0000x reference)
//
#include <hip/hip_runtime.h>
#include <math.h>

#define NB   4
#define LQ   5448
#define LSP  5440
#define NR   21792   // NB * LQ
#define DM   256

typedef unsigned short u16;
typedef __attribute__((ext_vector_type(8))) short short8;   // 8 bf16 (4 VGPR)
typedef __attribute__((ext_vector_type(4))) float f32x4;    // MFMA acc
typedef __attribute__((ext_vector_type(4))) unsigned int uint4v; // 16B move

__device__ __forceinline__ u16 f2bf(float f) {
  unsigned int u = __float_as_uint(f);
  u = (u + 0x7fff + ((u >> 16) & 1)) >> 16;   // RNE
  return (u16)u;
}
__device__ __forceinline__ float bf2f(u16 u) {
  return __uint_as_float(((unsigned int)u) << 16);
}
__device__ __forceinline__ uint4v pack8(float4 a, float4 b) {
  uint4v r;
  r.x = (unsigned)f2bf(a.x) | ((unsigned)f2bf(a.y) << 16);
  r.y = (unsigned)f2bf(a.z) | ((unsigned)f2bf(a.w) << 16);
  r.z = (unsigned)f2bf(b.x) | ((unsigned)f2bf(b.y) << 16);
  r.w = (unsigned)f2bf(b.z) | ((unsigned)f2bf(b.w) << 16);
  return r;
}

// async global->LDS 16B per lane (m97 pattern). lds ptr must be wave-uniform.
__device__ __forceinline__ void gld_lds16(const u16* g, u16* l) {
  __builtin_amdgcn_global_load_lds(
      (const __attribute__((address_space(1))) void*)g,
      (__attribute__((address_space(3))) void*)l, 16, 0, 0);
}

// ---------------- workspace layout (bytes) ----------------
// R0: oa (NR*384 f32 = 33.5MB) -> h_bf (NR*1024 bf16 = 44.6MB)
// R1: samp_bf (NR*256 bf16)
// R2: x_bf
// R3: val_bf
#define OFF_R0 0ull
#define OFF_R1 44630016ull
#define OFF_R2 55787520ull
#define OFF_R3 66945024ull
#define OFF_WB 78102528ull
#define OFF_BI 79609856ull

// weight sub-offsets (bf16 elems)
#define WOF_V  0
#define WOF_OA 65536
#define WOF_P  163840
#define WOF_1  229376
#define WOF_2  491520
#define NWELEM 753664

#define OUT0 5570560ull   // 4*5440*256
#define OUT1 614400ull    // 4*75*8*256

// ---------------------------------------------------------------------------
// Weight fp32 -> bf16 pack + fused [bo;ba] bias pack.
// ---------------------------------------------------------------------------
__global__ __launch_bounds__(256) void convw_k(
    const float* __restrict__ Wv, const float* __restrict__ Wo,
    const float* __restrict__ Wa, const float* __restrict__ Wp,
    const float* __restrict__ W1, const float* __restrict__ W2,
    const float* __restrict__ bo, const float* __restrict__ ba,
    u16* __restrict__ out, float* __restrict__ boa)
{
  const int gid = blockIdx.x * 256 + threadIdx.x;
  if (gid < 384) boa[gid] = (gid < 256) ? bo[gid] : ba[gid - 256];
  if (gid >= NWELEM) return;
  float v;
  if (gid < WOF_OA) {
    v = Wv[gid];
  } else if (gid < WOF_P) {
    const int o = gid - WOF_OA;
    v = (o < 65536) ? Wo[o] : Wa[o - 65536];
  } else if (gid < WOF_1) {
    v = Wp[gid - WOF_P];
  } else if (gid < WOF_2) {
    v = W1[gid - WOF_1];
  } else {
    v = W2[gid - WOF_2];
  }
  out[gid] = f2bf(v);
}

// ---------------------------------------------------------------------------
// Full-chunk-staged MFMA GEMM. BM=64, BK=128, BN = WC*64 (WC=4 -> 80KB LDS,
// 2 blocks/CU; WC=6 -> 112KB, 1 block/CU). Per chunk: issue ALL staging
// (global_load_lds for bf16, deep manual fp32->bf16 for A-modes) back-to-back
// -> ~80KB in flight per block (fixes the MLP wall measured in r5: all
// kernels plateaued at ~1.1 TB/s effective), one barrier, LDS-fed MFMA.
// LDS image per ktile: [64|BN rows][32], granule-XOR swizzle (r3-proven):
// phys granule p of row r holds global granule p^((r>>1)&3); DMA-compatible.
// AMODE: 0 A ptr bf16; 1 q-row (src+pos|sel) fused; 2 vin-row (src|sel).
// EPI: 0 bf16; 1 relu bf16; 2 LN1(res src/sel)->bf16; 3 LN2(res xbf)->fp32
// scatter to d_out; 4 fp32 out (ldof).
// ---------------------------------------------------------------------------
template <int AMODE, int EPI, int WC>
__global__ __launch_bounds__(256) void gemmF(
    const u16* __restrict__ A, int lda,
    const float* __restrict__ src, const float* __restrict__ pos,
    const float* __restrict__ sel,
    const u16* __restrict__ B, int ldb,
    const float* __restrict__ bias, int K,
    u16* __restrict__ outb, int ldob,
    const u16* __restrict__ xbf,
    const float* __restrict__ gvec, const float* __restrict__ bvec,
    float* __restrict__ outf, int ldof)
{
  constexpr int BN = WC * 64;
  __shared__ u16 As[4 * 64 * 32];     // 16 KB, 4 ktiles
  __shared__ u16 Bs[4 * BN * 32];     // 64/96 KB
  const int tid = threadIdx.x;
  const int w = tid >> 6, lane = tid & 63;
  const int l15 = lane & 15, quad = lane >> 4;
  const int m0 = blockIdx.y * 64;
  const int n0 = blockIdx.x * BN;
  const int swz = (quad ^ ((l15 >> 1) & 3)) * 8;
  const int ga8 = ((lane & 3) ^ ((lane >> 3) & 3)) * 8;
  const int seglane = lane >> 2;

  // A DMA row (AMODE 0): wave w stages segment w of the 64 A-rows
  int gmA = m0 + w * 16 + seglane; if (gmA >= NR) gmA = NR - 1;

  // manual A staging ids (AMODE 1/2): thread -> (row rA, granule pA)
  const int rA = tid >> 2, pA = tid & 3;
  const int cA = (pA ^ ((rA >> 1) & 3)) * 8;
  const int ldsA = rA * 32 + pA * 8;
  const float *aV = nullptr, *aP = nullptr;
  if (AMODE) {
    int gm = m0 + rA; if (gm >= NR) gm = NR - 1;
    const int n = gm / LQ, i = gm - n * LQ;
    if (i < LSP) {
      aV = src + ((size_t)(n * LSP + i)) * DM;
      if (AMODE == 1) aP = pos + ((size_t)(n * LSP + i)) * DM;
    } else {
      aV = sel + ((size_t)(n * 8 + (i - LSP))) * DM;
    }
  }

  f32x4 acc[4][WC] = {};

  for (int kc = 0; kc < K; kc += 128) {
    if (kc) __syncthreads();
    // ---- A manual loads (fp32 paths): issue all 8(+8) loads up front ----
    float4 av[4][2], pv[4][2];
    if (AMODE) {
#pragma unroll
      for (int kt = 0; kt < 4; ++kt) {
        av[kt][0] = *(const float4*)(aV + kc + kt * 32 + cA);
        av[kt][1] = *(const float4*)(aV + kc + kt * 32 + cA + 4);
      }
      if (AMODE == 1) {
        if (aP) {
#pragma unroll
          for (int kt = 0; kt < 4; ++kt) {
            pv[kt][0] = *(const float4*)(aP + kc + kt * 32 + cA);
            pv[kt][1] = *(const float4*)(aP + kc + kt * 32 + cA + 4);
          }
        } else {
#pragma unroll
          for (int kt = 0; kt < 4; ++kt) {
            pv[kt][0] = make_float4(0.f, 0.f, 0.f, 0.f);
            pv[kt][1] = make_float4(0.f, 0.f, 0.f, 0.f);
          }
        }
      }
    }
    // ---- all DMA staging issued back-to-back (deep MLP) ----
#pragma unroll
    for (int kt = 0; kt < 4; ++kt) {
      if (AMODE == 0)
        gld_lds16(A + (size_t)gmA * lda + kc + kt * 32 + ga8,
                  &As[kt * 2048 + w * 512]);
      for (int s = w; s < BN / 16; s += 4)
        gld_lds16(B + (size_t)(n0 + s * 16 + seglane) * ldb + kc + kt * 32 + ga8,
                  &Bs[kt * BN * 32 + s * 512]);
    }
    // ---- A pack + LDS write (fp32 paths) ----
    if (AMODE) {
#pragma unroll
      for (int kt = 0; kt < 4; ++kt) {
        float4 a0 = av[kt][0], a1 = av[kt][1];
        if (AMODE == 1) {
          a0.x += pv[kt][0].x; a0.y += pv[kt][0].y;
          a0.z += pv[kt][0].z; a0.w += pv[kt][0].w;
          a1.x += pv[kt][1].x; a1.y += pv[kt][1].y;
          a1.z += pv[kt][1].z; a1.w += pv[kt][1].w;
        }
        *(uint4v*)&As[kt * 2048 + ldsA] = pack8(a0, a1);
      }
    }
    __syncthreads();
    // ---- LDS-fed MFMA, no barriers ----
#pragma unroll
    for (int kt = 0; kt < 4; ++kt) {
      short8 af[4], bfr[WC];
#pragma unroll
      for (int r = 0; r < 4; ++r)
        af[r] = *(const short8*)&As[kt * 2048 + (r * 16 + l15) * 32 + swz];
#pragma unroll
      for (int c = 0; c < WC; ++c)
        bfr[c] = *(const short8*)&Bs[kt * BN * 32 + (w * WC * 16 + c * 16 + l15) * 32 + swz];
#pragma unroll
      for (int r = 0; r < 4; ++r)
#pragma unroll
        for (int c = 0; c < WC; ++c)
          acc[r][c] = __builtin_amdgcn_mfma_f32_16x16x32_bf16(af[r], bfr[c], acc[r][c], 0, 0, 0);
    }
  }

  // ---------------- epilogues ----------------
  int col[WC];
  float bb[WC];
#pragma unroll
  for (int c = 0; c < WC; ++c) {
    col[c] = n0 + w * WC * 16 + c * 16 + l15;
    bb[c] = bias[col[c]];
  }

  if (EPI == 4) {
#pragma unroll
    for (int c = 0; c < WC; ++c)
#pragma unroll
      for (int r = 0; r < 4; ++r)
#pragma unroll
        for (int j = 0; j < 4; ++j) {
          const int row = m0 + r * 16 + quad * 4 + j;
          if (row < NR) outf[(size_t)row * ldof + col[c]] = acc[r][c][j] + bb[c];
        }
    return;
  }

  if (EPI <= 1) {
#pragma unroll
    for (int c = 0; c < WC; ++c)
#pragma unroll
      for (int r = 0; r < 4; ++r)
#pragma unroll
        for (int j = 0; j < 4; ++j) {
          const int row = m0 + r * 16 + quad * 4 + j;
          if (row < NR) {
            float v = acc[r][c][j] + bb[c];
            if (EPI == 1) v = fmaxf(v, 0.f);
            outb[(size_t)row * ldob + col[c]] = f2bf(v);
          }
        }
    return;
  }

  // ---- EPI 2/3: residual + LayerNorm fused epilogue (WC=4 only) ----
  __syncthreads();   // done reading As -> reuse as scratch
  float sv[4][4], sq[4][4];
#pragma unroll
  for (int r = 0; r < 4; ++r) {
#pragma unroll
    for (int j = 0; j < 4; ++j) {
      const int row = m0 + r * 16 + quad * 4 + j;
      const int rc = (row < NR) ? row : NR - 1;
      if (EPI == 2) {
        const int n = rc / LQ;
        const int i = rc - n * LQ;
        const float* resb = (i < LSP)
            ? src + ((size_t)(n * LSP + i)) * DM
            : sel + ((size_t)(n * 8 + (i - LSP))) * DM;
#pragma unroll
        for (int c = 0; c < WC; ++c) acc[r][c][j] += bb[c] + resb[col[c]];
      } else {
#pragma unroll
        for (int c = 0; c < WC; ++c)
          acc[r][c][j] += bb[c] + bf2f(xbf[(size_t)rc * DM + col[c]]);
      }
      float s = 0.f, q = 0.f;
#pragma unroll
      for (int c = 0; c < WC; ++c) {
        const float v = acc[r][c][j];
        s += v; q += v * v;
      }
      sv[r][j] = s; sq[r][j] = q;
    }
  }
#pragma unroll
  for (int off = 1; off < 16; off <<= 1) {
#pragma unroll
    for (int r = 0; r < 4; ++r)
#pragma unroll
      for (int j = 0; j < 4; ++j) {
        sv[r][j] += __shfl_xor(sv[r][j], off, 64);
        sq[r][j] += __shfl_xor(sq[r][j], off, 64);
      }
  }
  float* red = (float*)As;   // [64 rows][4 waves][2]
  if (l15 == 0) {
#pragma unroll
    for (int r = 0; r < 4; ++r)
#pragma unroll
      for (int j = 0; j < 4; ++j) {
        const int rl = r * 16 + quad * 4 + j;
        red[(rl * 4 + w) * 2 + 0] = sv[r][j];
        red[(rl * 4 + w) * 2 + 1] = sq[r][j];
      }
  }
  __syncthreads();

  float gg[WC], b2[WC];
#pragma unroll
  for (int c = 0; c < WC; ++c) { gg[c] = gvec[col[c]]; b2[c] = bvec[col[c]]; }

#pragma unroll
  for (int r = 0; r < 4; ++r) {
#pragma unroll
    for (int j = 0; j < 4; ++j) {
      const int row = m0 + r * 16 + quad * 4 + j;
      if (row >= NR) continue;
      const int rl = r * 16 + quad * 4 + j;
      float ms = 0.f, mq = 0.f;
#pragma unroll
      for (int ww = 0; ww < 4; ++ww) {
        ms += red[(rl * 4 + ww) * 2 + 0];
        mq += red[(rl * 4 + ww) * 2 + 1];
      }
      const float mean = ms * (1.f / 256.f);
      const float var = mq * (1.f / 256.f) - mean * mean;
      const float rin = rsqrtf(var + 1e-5f);
      if (EPI == 2) {
#pragma unroll
        for (int c = 0; c < WC; ++c)
          outb[(size_t)row * DM + col[c]] =
              f2bf(gg[c] * (acc[r][c][j] - mean) * rin + b2[c]);
      } else {
        const int n = row / LQ;
        const int i = row - n * LQ;
        float* dst = (i < LSP)
            ? outf + (size_t)(n * LSP + i) * DM
            : outf + OUT0 + OUT1 + (size_t)(n * 8 + (i - LSP)) * DM;
#pragma unroll
        for (int c = 0; c < WC; ++c)
          dst[col[c]] = gg[c] * (acc[r][c][j] - mean) * rin + b2[c];
      }
    }
  }
}

// ---------------------------------------------------------------------------
// Deformable sampling v4: branchless (clamped addresses + zeroed weights),
// per-level batched gathers (16 loads in flight). XCD-affine block mapping;
// softmax fused. 32 lanes per row (m = head, q4 = 8-dim slice).
// ---------------------------------------------------------------------------
__device__ __forceinline__ void acc8w(float* a, const uint4v u, float w) {
  a[0] += w * __uint_as_float((u.x & 0xffffu) << 16);
  a[1] += w * __uint_as_float(u.x & 0xffff0000u);
  a[2] += w * __uint_as_float((u.y & 0xffffu) << 16);
  a[3] += w * __uint_as_float(u.y & 0xffff0000u);
  a[4] += w * __uint_as_float((u.z & 0xffffu) << 16);
  a[5] += w * __uint_as_float(u.z & 0xffff0000u);
  a[6] += w * __uint_as_float((u.w & 0xffffu) << 16);
  a[7] += w * __uint_as_float(u.w & 0xffff0000u);
}

__global__ __launch_bounds__(256) void sample4_k(
    const u16* __restrict__ value, const float* __restrict__ oa,
    const float* __restrict__ ref, u16* __restrict__ samp)
{
  const int lb = blockIdx.x;
  const int xcd = lb & 7;
  const int idx = lb >> 3;
  const int batch = xcd >> 1;
  const int rg = idx * 2 + (xcd & 1);
  if (rg >= 681) return;
  const int lane = threadIdx.x & 63;
  const int li = threadIdx.x & 31;
  const int m = li >> 2, q4 = li & 3;
  const int row = batch * LQ + rg * 8 + (threadIdx.x >> 5);

  const float* oar = oa + (size_t)row * 384;
  const float* offm = oar + m * 32;

  // fused softmax: lane q4 owns level q4's 4 point-weights
  const float4 lg = *(const float4*)(oar + 256 + m * 16 + q4 * 4);
  float mx = fmaxf(fmaxf(lg.x, lg.y), fmaxf(lg.z, lg.w));
  mx = fmaxf(mx, __shfl_xor(mx, 1, 64));
  mx = fmaxf(mx, __shfl_xor(mx, 2, 64));
  const float e0 = __expf(lg.x - mx), e1 = __expf(lg.y - mx),
              e2 = __expf(lg.z - mx), e3 = __expf(lg.w - mx);
  float s = e0 + e1 + e2 + e3;
  s += __shfl_xor(s, 1, 64);
  s += __shfl_xor(s, 2, 64);
  const float inv = 1.f / s;
  float wp[4] = {e0 * inv, e1 * inv, e2 * inv, e3 * inv};

  const float4 r01 = *(const float4*)(ref + (size_t)row * 8);
  const float4 r23 = *(const float4*)(ref + (size_t)row * 8 + 4);
  const float RX[4] = {r01.x, r01.z, r23.x, r23.z};
  const float RY[4] = {r01.y, r01.w, r23.y, r23.w};
  const int HW[4] = {64, 32, 16, 8};
  const int ST[4] = {0, 4096, 5120, 5376};

  float a[8] = {};
#pragma unroll
  for (int l = 0; l < 4; ++l) {
    const int W = HW[l];
    const float rx = RX[l], ry = RY[l];
    const u16* vb = value + ((size_t)(batch * LQ + ST[l])) * DM + m * 32 + q4 * 8;
    const float4 oA = *(const float4*)(offm + l * 8);
    const float4 oB = *(const float4*)(offm + l * 8 + 4);
    const float ox[4] = {oA.x, oA.z, oB.x, oB.z};
    const float oy[4] = {oA.y, oA.w, oB.y, oB.w};
    int idx16[16];
    float wt16[16];
#pragma unroll
    for (int p = 0; p < 4; ++p) {
      const float aw = __shfl(wp[p], (lane & ~3) | l, 64);
      const float px = rx * (float)W + ox[p] - 0.5f;
      const float py = ry * (float)W + oy[p] - 0.5f;
      const float xf = floorf(px), yf = floorf(py);
      const float wx = px - xf, wy = py - yf;
      const int x0 = (int)xf, y0 = (int)yf;
      const int x1 = x0 + 1, y1 = y0 + 1;
      const int x0c = min(max(x0, 0), W - 1), x1c = min(max(x1, 0), W - 1);
      const int y0c = min(max(y0, 0), W - 1), y1c = min(max(y1, 0), W - 1);
      const bool vx0 = (x0 == x0c), vx1 = (x1 == x1c);
      const bool vy0 = (y0 == y0c), vy1 = (y1 == y1c);
      const float wxa = aw * wx, wxb = aw * (1.f - wx);
      wt16[p * 4 + 0] = (vx0 & vy0) ? wxb * (1.f - wy) : 0.f;
      wt16[p * 4 + 1] = (vx1 & vy0) ? wxa * (1.f - wy) : 0.f;
      wt16[p * 4 + 2] = (vx0 & vy1) ? wxb * wy : 0.f;
      wt16[p * 4 + 3] = (vx1 & vy1) ? wxa * wy : 0.f;
      idx16[p * 4 + 0] = y0c * W + x0c;
      idx16[p * 4 + 1] = y0c * W + x1c;
      idx16[p * 4 + 2] = y1c * W + x0c;
      idx16[p * 4 + 3] = y1c * W + x1c;
    }
    uint4v d[16];
#pragma unroll
    for (int i = 0; i < 16; ++i)
      d[i] = *(const uint4v*)(vb + (size_t)idx16[i] * DM);
#pragma unroll
    for (int i = 0; i < 16; ++i) acc8w(a, d[i], wt16[i]);
  }
  uint4v ov;
  ov.x = (unsigned int)f2bf(a[0]) | ((unsigned int)f2bf(a[1]) << 16);
  ov.y = (unsigned int)f2bf(a[2]) | ((unsigned int)f2bf(a[3]) << 16);
  ov.z = (unsigned int)f2bf(a[4]) | ((unsigned int)f2bf(a[5]) << 16);
  ov.w = (unsigned int)f2bf(a[6]) | ((unsigned int)f2bf(a[7]) << 16);
  *(uint4v*)(samp + (size_t)row * DM + m * 32 + q4 * 8) = ov;
}

// ---------------------------------------------------------------------------
extern "C" void kernel_launch(void* const* d_in, const int* in_sizes, int n_in,
                              void* d_out, int out_size, void* d_ws, size_t ws_size,
                              hipStream_t stream)
{
  const float* src = (const float*)d_in[0];
  const float* pos = (const float*)d_in[1];
  const float* ref = (const float*)d_in[2];
  const float* all_vt = (const float*)d_in[6];
  const float* sel = (const float*)d_in[7];
  const float* Wv = (const float*)d_in[8];
  const float* bv = (const float*)d_in[9];
  const float* Wo = (const float*)d_in[10];
  const float* bo = (const float*)d_in[11];
  const float* Wa = (const float*)d_in[12];
  const float* ba = (const float*)d_in[13];
  const float* Wp = (const float*)d_in[14];
  const float* bp = (const float*)d_in[15];
  const float* g1 = (const float*)d_in[16];
  const float* be1 = (const float*)d_in[17];
  const float* W1 = (const float*)d_in[18];
  const float* b1 = (const float*)d_in[19];
  const float* W2 = (const float*)d_in[20];
  const float* b2 = (const float*)d_in[21];
  const float* g2 = (const float*)d_in[22];
  const float* be2 = (const float*)d_in[23];

  char* ws = (char*)d_ws;
  float* oabuf = (float*)(ws + OFF_R0);   // dead after sample4
  u16* h_bf    = (u16*)(ws + OFF_R0);     // written by ffn1 (after oa dead)
  u16* samp_bf = (u16*)(ws + OFF_R1);
  u16* x_bf    = (u16*)(ws + OFF_R2);
  u16* val_bf  = (u16*)(ws + OFF_R3);
  u16* WB      = (u16*)(ws + OFF_WB);
  float* boa   = (float*)(ws + OFF_BI);

  const dim3 b256(256);
  const int MT64 = (NR + 63) / 64;    // 341

  convw_k<<<dim3(NWELEM / 256), b256, 0, stream>>>(
      Wv, Wo, Wa, Wp, W1, W2, bo, ba, WB, boa);
  // value = vin @ Wv^T + bv  (A = src|sel fused fp32->bf16; bf16 out)
  gemmF<2, 0, 4><<<dim3(1, MT64), b256, 0, stream>>>(
      nullptr, 0, src, nullptr, sel, WB + WOF_V, 256, bv, 256,
      val_bf, 256, nullptr, nullptr, nullptr, nullptr, 0);
  // [off | attn] = q @ [Wo;Wa]^T + [bo;ba]  (A = src+pos|sel; fp32, ldc=384)
  gemmF<1, 4, 6><<<dim3(1, MT64), b256, 0, stream>>>(
      nullptr, 0, src, pos, sel, WB + WOF_OA, 256, boa, 256,
      nullptr, 0, nullptr, nullptr, nullptr, oabuf, 384);
  // sampling (softmax fused, branchless batched gathers)
  sample4_k<<<dim3(8 * 341), b256, 0, stream>>>(val_bf, oabuf, ref, samp_bf);
  // x = LN(v_in + samp @ Wp^T + bp) -> x_bf   (LN1 fused epilogue)
  gemmF<0, 2, 4><<<dim3(1, MT64), b256, 0, stream>>>(
      samp_bf, 256, src, nullptr, sel, WB + WOF_P, 256, bp, 256,
      x_bf, 256, nullptr, g1, be1, nullptr, 0);
  // h = relu(x @ W1^T + b1)  N=1024 over 4 N-blocks, bf16
  gemmF<0, 1, 4><<<dim3(4, MT64), b256, 0, stream>>>(
      x_bf, 256, nullptr, nullptr, nullptr, WB + WOF_1, 256, b1, 256,
      h_bf, 1024, nullptr, nullptr, nullptr, nullptr, 0);
  // out = LN(x + h @ W2^T + b2) scattered to d_out  (LN2 fused epilogue)
  gemmF<0, 3, 4><<<dim3(1, MT64), b256, 0, stream>>>(
      h_bf, 1024, nullptr, nullptr, nullptr, WB + WOF_2, 1024, b2, 1024,
      nullptr, 0, x_bf, g2, be2, (float*)d_out, 0);
  // all_vt pass-through
  hipMemcpyAsync((float*)d_out + OUT0, all_vt, OUT1 * sizeof(float),
                 hipMemcpyDeviceToDevice, stream);
}

// Round 7
// 324.852 us; speedup vs baseline: 1.2104x; 1.2104x over previous
//
#include <hip/hip_runtime.h>
#include <math.h>

#define NB   4
#define LQ   5448
#define LSP  5440
#define NR   21792   // NB * LQ
#define DM   256

typedef unsigned short u16;
typedef __attribute__((ext_vector_type(8))) short short8;   // 8 bf16 (4 VGPR)
typedef __attribute__((ext_vector_type(4))) float f32x4;    // MFMA acc
typedef __attribute__((ext_vector_type(4))) unsigned int uint4v; // 16B move

__device__ __forceinline__ u16 f2bf(float f) {
  unsigned int u = __float_as_uint(f);
  u = (u + 0x7fff + ((u >> 16) & 1)) >> 16;   // RNE
  return (u16)u;
}
__device__ __forceinline__ float bf2f(u16 u) {
  return __uint_as_float(((unsigned int)u) << 16);
}

// async global->LDS 16B per lane (m97 pattern). lds ptr must be wave-uniform.
__device__ __forceinline__ void gld_lds16(const u16* g, u16* l) {
  __builtin_amdgcn_global_load_lds(
      (const __attribute__((address_space(1))) void*)g,
      (__attribute__((address_space(3))) void*)l, 16, 0, 0);
}

// ---------------- workspace layout (bytes) ----------------
#define OFF_R0 0ull           // oa (NR*384 f32 = 33.5MB) -> h_bf (NR*1024 bf16)
#define OFF_R1 44630016ull    // vin_bf -> s2_bf
#define OFF_R2 55787520ull    // q_bf -> x_bf
#define OFF_R3 66945024ull    // val_bf -> y_bf
#define OFF_R4 78102528ull    // samp_bf
#define OFF_WB 89260032ull    // packed bf16 weights
#define OFF_BI 90767360ull    // packed bias_oa (384 f32)
// total ~90.8 MB

// weight sub-offsets (bf16 elems)
#define WOF_V  0
#define WOF_OA 65536
#define WOF_P  163840
#define WOF_1  229376
#define WOF_2  491520
#define NWELEM 753664

#define OUT0 5570560ull   // 4*5440*256
#define OUT1 614400ull    // 4*75*8*256

// ---------------------------------------------------------------------------
// Weight fp32 -> bf16 pack + fused [bo;ba] bias pack.
// ---------------------------------------------------------------------------
__global__ __launch_bounds__(256) void convw_k(
    const float* __restrict__ Wv, const float* __restrict__ Wo,
    const float* __restrict__ Wa, const float* __restrict__ Wp,
    const float* __restrict__ W1, const float* __restrict__ W2,
    const float* __restrict__ bo, const float* __restrict__ ba,
    u16* __restrict__ out, float* __restrict__ boa)
{
  const int gid = blockIdx.x * 256 + threadIdx.x;
  if (gid < 384) boa[gid] = (gid < 256) ? bo[gid] : ba[gid - 256];
  if (gid >= NWELEM) return;
  float v;
  if (gid < WOF_OA) {
    v = Wv[gid];
  } else if (gid < WOF_P) {
    const int o = gid - WOF_OA;
    v = (o < 65536) ? Wo[o] : Wa[o - 65536];
  } else if (gid < WOF_1) {
    v = Wp[gid - WOF_P];
  } else if (gid < WOF_2) {
    v = W1[gid - WOF_1];
  } else {
    v = W2[gid - WOF_2];
  }
  out[gid] = f2bf(v);
}

// ---------------------------------------------------------------------------
// Build q_bf (src+pos | sel) and vin_bf (src | sel). 4 rows/block, wave/row.
// ---------------------------------------------------------------------------
__global__ __launch_bounds__(256) void qv_build_k(
    const float* __restrict__ src, const float* __restrict__ pos,
    const float* __restrict__ sel,
    u16* __restrict__ qb, u16* __restrict__ vb)
{
  const int row = blockIdx.x * 4 + (threadIdx.x >> 6);
  const int t = threadIdx.x & 63;
  const int n = row / LQ;
  const int i = row - n * LQ;
  float4 v, p = make_float4(0.f, 0.f, 0.f, 0.f);
  if (i < LSP) {
    const size_t o = ((size_t)(n * LSP + i)) * DM + t * 4;
    v = *(const float4*)(src + o);
    p = *(const float4*)(pos + o);
  } else {
    v = *(const float4*)(sel + ((size_t)(n * 8 + (i - LSP))) * DM + t * 4);
  }
  ushort4 vq, vv;
  vv.x = f2bf(v.x); vv.y = f2bf(v.y); vv.z = f2bf(v.z); vv.w = f2bf(v.w);
  vq.x = f2bf(v.x + p.x); vq.y = f2bf(v.y + p.y);
  vq.z = f2bf(v.z + p.z); vq.w = f2bf(v.w + p.w);
  *(ushort4*)(vb + (size_t)row * DM + t * 4) = vv;
  *(ushort4*)(qb + (size_t)row * DM + t * 4) = vq;
}

// ---------------------------------------------------------------------------
// Small-block MFMA GEMM: BM=64, BN=64, BK=128, 32 KB LDS -> 5 blocks/CU
// resident (the r4-r6 341-block structures starved at 1.33 blocks/CU; this
// trades intra-block cleverness for inter-block TLP). 4 waves; wave w owns
// rows [m0+w*16, +16) x all 64 cols; acc = 4 x f32x4 (16 VGPR).
// LDS image per ktile: [64 rows][32 elems], granule-XOR swizzle (r3-proven,
// DMA-compatible): phys granule p of row r holds global granule p^((r%16)>>1&3).
// EPI: 0 bf16 out; 1 relu bf16 out; 4 fp32 out.
// ---------------------------------------------------------------------------
template <int EPI>
__global__ __launch_bounds__(256) void gemm64(
    const u16* __restrict__ A, int lda,
    const u16* __restrict__ B, int ldb,
    const float* __restrict__ bias, int K,
    u16* __restrict__ outb, float* __restrict__ outf, int ldo)
{
  __shared__ u16 As[4 * 64 * 32];   // 16 KB (4 ktiles of 64x32)
  __shared__ u16 Bs[4 * 64 * 32];   // 16 KB
  const int tid = threadIdx.x;
  const int w = tid >> 6, lane = tid & 63;
  const int l15 = lane & 15, quad = lane >> 4;
  const int m0 = blockIdx.y * 64;
  const int n0 = blockIdx.x * 64;
  const int swz = (quad ^ ((l15 >> 1) & 3)) * 8;
  const int ga8 = ((lane & 3) ^ ((lane >> 3) & 3)) * 8;
  const int seg = lane >> 2;

  int gmA = m0 + w * 16 + seg; if (gmA >= NR) gmA = NR - 1;
  const int gnB = n0 + w * 16 + seg;   // N is a multiple of 64

  f32x4 acc[4] = {};

  for (int kc = 0; kc < K; kc += 128) {
    if (kc) __syncthreads();
    // stage the full 64x128 A and B chunks: 8 DMA instr/wave back-to-back
#pragma unroll
    for (int kt = 0; kt < 4; ++kt) {
      gld_lds16(A + (size_t)gmA * lda + kc + kt * 32 + ga8,
                &As[kt * 2048 + w * 512]);
      gld_lds16(B + (size_t)gnB * ldb + kc + kt * 32 + ga8,
                &Bs[kt * 2048 + w * 512]);
    }
    __syncthreads();
#pragma unroll
    for (int kt = 0; kt < 4; ++kt) {
      const short8 af = *(const short8*)&As[kt * 2048 + (w * 16 + l15) * 32 + swz];
#pragma unroll
      for (int c = 0; c < 4; ++c) {
        const short8 bf = *(const short8*)&Bs[kt * 2048 + (c * 16 + l15) * 32 + swz];
        acc[c] = __builtin_amdgcn_mfma_f32_16x16x32_bf16(af, bf, acc[c], 0, 0, 0);
      }
    }
  }

#pragma unroll
  for (int c = 0; c < 4; ++c) {
    const int col = n0 + c * 16 + l15;
    const float bb = bias[col];
#pragma unroll
    for (int j = 0; j < 4; ++j) {
      const int row = m0 + w * 16 + quad * 4 + j;
      if (row < NR) {
        float v = acc[c][j] + bb;
        if (EPI == 1) v = fmaxf(v, 0.f);
        if (EPI == 4) outf[(size_t)row * ldo + col] = v;
        else          outb[(size_t)row * ldo + col] = f2bf(v);
      }
    }
  }
}

// ---------------------------------------------------------------------------
// Deformable sampling v3 (r3/r5-proven: 57.6us, VGPR 28). XCD-affine block
// mapping (per-XCD working set < 4MiB L2); softmax fused.
// ---------------------------------------------------------------------------
__device__ __forceinline__ void acc8(float* a, const u16* p, float w) {
  const uint4v u = *(const uint4v*)p;
  a[0] += w * __uint_as_float((u.x & 0xffffu) << 16);
  a[1] += w * __uint_as_float(u.x & 0xffff0000u);
  a[2] += w * __uint_as_float((u.y & 0xffffu) << 16);
  a[3] += w * __uint_as_float(u.y & 0xffff0000u);
  a[4] += w * __uint_as_float((u.z & 0xffffu) << 16);
  a[5] += w * __uint_as_float(u.z & 0xffff0000u);
  a[6] += w * __uint_as_float((u.w & 0xffffu) << 16);
  a[7] += w * __uint_as_float(u.w & 0xffff0000u);
}

__global__ __launch_bounds__(256) void sample3_k(
    const u16* __restrict__ value, const float* __restrict__ oa,
    const float* __restrict__ ref, u16* __restrict__ samp)
{
  const int lb = blockIdx.x;
  const int xcd = lb & 7;
  const int idx = lb >> 3;
  const int batch = xcd >> 1;
  const int rg = idx * 2 + (xcd & 1);
  if (rg >= 681) return;
  const int lane = threadIdx.x & 63;
  const int li = threadIdx.x & 31;
  const int m = li >> 2, q4 = li & 3;
  const int row = batch * LQ + rg * 8 + (threadIdx.x >> 5);

  const float* oar = oa + (size_t)row * 384;
  const float* offm = oar + m * 32;

  const float4 lg = *(const float4*)(oar + 256 + m * 16 + q4 * 4);
  float mx = fmaxf(fmaxf(lg.x, lg.y), fmaxf(lg.z, lg.w));
  mx = fmaxf(mx, __shfl_xor(mx, 1, 64));
  mx = fmaxf(mx, __shfl_xor(mx, 2, 64));
  const float e0 = __expf(lg.x - mx), e1 = __expf(lg.y - mx),
              e2 = __expf(lg.z - mx), e3 = __expf(lg.w - mx);
  float s = e0 + e1 + e2 + e3;
  s += __shfl_xor(s, 1, 64);
  s += __shfl_xor(s, 2, 64);
  const float inv = 1.f / s;
  float wp[4] = {e0 * inv, e1 * inv, e2 * inv, e3 * inv};

  const float4 r01 = *(const float4*)(ref + (size_t)row * 8);
  const float4 r23 = *(const float4*)(ref + (size_t)row * 8 + 4);
  const float RX[4] = {r01.x, r01.z, r23.x, r23.z};
  const float RY[4] = {r01.y, r01.w, r23.y, r23.w};
  const int HW[4] = {64, 32, 16, 8};
  const int ST[4] = {0, 4096, 5120, 5376};

  float a[8] = {};
#pragma unroll
  for (int l = 0; l < 4; ++l) {
    const int W = HW[l], H = HW[l];
    const float rx = RX[l], ry = RY[l];
    const u16* vb = value + ((size_t)(batch * LQ + ST[l])) * DM + m * 32 + q4 * 8;
    const float4 oA = *(const float4*)(offm + l * 8);
    const float4 oB = *(const float4*)(offm + l * 8 + 4);
    const float ox[4] = {oA.x, oA.z, oB.x, oB.z};
    const float oy[4] = {oA.y, oA.w, oB.y, oB.w};
#pragma unroll
    for (int p = 0; p < 4; ++p) {
      const float aw = __shfl(wp[p], (lane & ~3) | l, 64);
      const float px = rx * (float)W + ox[p] - 0.5f;
      const float py = ry * (float)H + oy[p] - 0.5f;
      const float xf = floorf(px), yf = floorf(py);
      const float wx = px - xf, wy = py - yf;
      const int x0 = (int)xf, y0 = (int)yf;
      const int x1 = x0 + 1, y1 = y0 + 1;
      const bool vx0 = (x0 >= 0) & (x0 < W), vx1 = (x1 >= 0) & (x1 < W);
      const bool vy0 = (y0 >= 0) & (y0 < H), vy1 = (y1 >= 0) & (y1 < H);
      if (vy0 & vx0) acc8(a, vb + (size_t)(y0 * W + x0) * DM, aw * (1.f - wx) * (1.f - wy));
      if (vy0 & vx1) acc8(a, vb + (size_t)(y0 * W + x1) * DM, aw * wx * (1.f - wy));
      if (vy1 & vx0) acc8(a, vb + (size_t)(y1 * W + x0) * DM, aw * (1.f - wx) * wy);
      if (vy1 & vx1) acc8(a, vb + (size_t)(y1 * W + x1) * DM, aw * wx * wy);
    }
  }
  uint4v ov;
  ov.x = (unsigned int)f2bf(a[0]) | ((unsigned int)f2bf(a[1]) << 16);
  ov.y = (unsigned int)f2bf(a[2]) | ((unsigned int)f2bf(a[3]) << 16);
  ov.z = (unsigned int)f2bf(a[4]) | ((unsigned int)f2bf(a[5]) << 16);
  ov.w = (unsigned int)f2bf(a[6]) | ((unsigned int)f2bf(a[7]) << 16);
  *(uint4v*)(samp + (size_t)row * DM + m * 32 + q4 * 8) = ov;
}

// ---------------------------------------------------------------------------
// LN1: x_bf = LN(v_in(src|sel fp32) + s2_bf). Wave per row, 4 rows/block.
// ---------------------------------------------------------------------------
__global__ __launch_bounds__(256) void ln1_k(
    const float* __restrict__ src, const float* __restrict__ sel,
    const u16* __restrict__ s2,
    const float* __restrict__ g, const float* __restrict__ b,
    u16* __restrict__ xbf)
{
  const int row = blockIdx.x * 4 + (threadIdx.x >> 6);
  const int t = threadIdx.x & 63;
  const int n = row / LQ;
  const int i = row - n * LQ;
  const float* vrow = (i < LSP) ? (src + (size_t)(n * LSP + i) * DM)
                                : (sel + (size_t)(n * 8 + (i - LSP)) * DM);
  float4 v = *(const float4*)(vrow + t * 4);
  const ushort4 sb = *(const ushort4*)(s2 + (size_t)row * DM + t * 4);
  v.x += bf2f(sb.x); v.y += bf2f(sb.y); v.z += bf2f(sb.z); v.w += bf2f(sb.w);
  float s = v.x + v.y + v.z + v.w;
#pragma unroll
  for (int o = 32; o > 0; o >>= 1) s += __shfl_xor(s, o, 64);
  const float mean = s * (1.f / 256.f);
  const float dx = v.x - mean, dy = v.y - mean, dz = v.z - mean, dw = v.w - mean;
  float q = dx * dx + dy * dy + dz * dz + dw * dw;
#pragma unroll
  for (int o = 32; o > 0; o >>= 1) q += __shfl_xor(q, o, 64);
  const float r = rsqrtf(q * (1.f / 256.f) + 1e-5f);
  const float4 gg = *(const float4*)(g + t * 4);
  const float4 bb = *(const float4*)(b + t * 4);
  ushort4 ob;
  ob.x = f2bf(gg.x * dx * r + bb.x);
  ob.y = f2bf(gg.y * dy * r + bb.y);
  ob.z = f2bf(gg.z * dz * r + bb.z);
  ob.w = f2bf(gg.w * dw * r + bb.w);
  *(ushort4*)(xbf + (size_t)row * DM + t * 4) = ob;
}

// ---------------------------------------------------------------------------
// LN2: out = LN(x_bf + y_bf) fp32, scattered to d_out (out0 | out2).
// ---------------------------------------------------------------------------
__global__ __launch_bounds__(256) void ln2_k(
    const u16* __restrict__ x, const u16* __restrict__ y,
    const float* __restrict__ g, const float* __restrict__ b,
    float* __restrict__ out)
{
  const int row = blockIdx.x * 4 + (threadIdx.x >> 6);
  const int t = threadIdx.x & 63;
  const int n = row / LQ;
  const int i = row - n * LQ;
  const ushort4 xv = *(const ushort4*)(x + (size_t)row * DM + t * 4);
  const ushort4 yv = *(const ushort4*)(y + (size_t)row * DM + t * 4);
  float4 v;
  v.x = bf2f(xv.x) + bf2f(yv.x);
  v.y = bf2f(xv.y) + bf2f(yv.y);
  v.z = bf2f(xv.z) + bf2f(yv.z);
  v.w = bf2f(xv.w) + bf2f(yv.w);
  float s = v.x + v.y + v.z + v.w;
#pragma unroll
  for (int o = 32; o > 0; o >>= 1) s += __shfl_xor(s, o, 64);
  const float mean = s * (1.f / 256.f);
  const float dx = v.x - mean, dy = v.y - mean, dz = v.z - mean, dw = v.w - mean;
  float q = dx * dx + dy * dy + dz * dz + dw * dw;
#pragma unroll
  for (int o = 32; o > 0; o >>= 1) q += __shfl_xor(q, o, 64);
  const float r = rsqrtf(q * (1.f / 256.f) + 1e-5f);
  const float4 gg = *(const float4*)(g + t * 4);
  const float4 bb = *(const float4*)(b + t * 4);
  float4 o4;
  o4.x = gg.x * dx * r + bb.x;
  o4.y = gg.y * dy * r + bb.y;
  o4.z = gg.z * dz * r + bb.z;
  o4.w = gg.w * dw * r + bb.w;
  float* dst = (i < LSP) ? (out + (size_t)(n * LSP + i) * DM)
                         : (out + OUT0 + OUT1 + (size_t)(n * 8 + (i - LSP)) * DM);
  *(float4*)(dst + t * 4) = o4;
}

// ---------------------------------------------------------------------------
extern "C" void kernel_launch(void* const* d_in, const int* in_sizes, int n_in,
                              void* d_out, int out_size, void* d_ws, size_t ws_size,
                              hipStream_t stream)
{
  const float* src = (const float*)d_in[0];
  const float* pos = (const float*)d_in[1];
  const float* ref = (const float*)d_in[2];
  const float* all_vt = (const float*)d_in[6];
  const float* sel = (const float*)d_in[7];
  const float* Wv = (const float*)d_in[8];
  const float* bv = (const float*)d_in[9];
  const float* Wo = (const float*)d_in[10];
  const float* bo = (const float*)d_in[11];
  const float* Wa = (const float*)d_in[12];
  const float* ba = (const float*)d_in[13];
  const float* Wp = (const float*)d_in[14];
  const float* bp = (const float*)d_in[15];
  const float* g1 = (const float*)d_in[16];
  const float* be1 = (const float*)d_in[17];
  const float* W1 = (const float*)d_in[18];
  const float* b1 = (const float*)d_in[19];
  const float* W2 = (const float*)d_in[20];
  const float* b2 = (const float*)d_in[21];
  const float* g2 = (const float*)d_in[22];
  const float* be2 = (const float*)d_in[23];

  char* ws = (char*)d_ws;
  float* oabuf = (float*)(ws + OFF_R0);   // dead after sample3
  u16* h_bf    = (u16*)(ws + OFF_R0);     // written by ffn1 (oa dead)
  u16* vin_bf  = (u16*)(ws + OFF_R1);     // -> s2_bf
  u16* s2_bf   = (u16*)(ws + OFF_R1);
  u16* q_bf    = (u16*)(ws + OFF_R2);     // -> x_bf
  u16* x_bf    = (u16*)(ws + OFF_R2);
  u16* val_bf  = (u16*)(ws + OFF_R3);     // -> y_bf
  u16* y_bf    = (u16*)(ws + OFF_R3);
  u16* samp_bf = (u16*)(ws + OFF_R4);
  u16* WB      = (u16*)(ws + OFF_WB);
  float* boa   = (float*)(ws + OFF_BI);

  const dim3 b256(256);
  const int MT = (NR + 63) / 64;    // 341

  convw_k<<<dim3(NWELEM / 256), b256, 0, stream>>>(
      Wv, Wo, Wa, Wp, W1, W2, bo, ba, WB, boa);
  qv_build_k<<<dim3(NR / 4), b256, 0, stream>>>(src, pos, sel, q_bf, vin_bf);
  // value = vin @ Wv^T + bv  (bf16)
  gemm64<0><<<dim3(4, MT), b256, 0, stream>>>(
      vin_bf, 256, WB + WOF_V, 256, bv, 256, val_bf, nullptr, 256);
  // [off | attn] = q @ [Wo;Wa]^T + [bo;ba]  (fp32, ldc=384)
  gemm64<4><<<dim3(6, MT), b256, 0, stream>>>(
      q_bf, 256, WB + WOF_OA, 256, boa, 256, nullptr, oabuf, 384);
  // sampling (softmax fused)
  sample3_k<<<dim3(8 * 341), b256, 0, stream>>>(val_bf, oabuf, ref, samp_bf);
  // s2 = samp @ Wp^T + bp  (bf16)
  gemm64<0><<<dim3(4, MT), b256, 0, stream>>>(
      samp_bf, 256, WB + WOF_P, 256, bp, 256, s2_bf, nullptr, 256);
  // x = LN(v_in + s2)
  ln1_k<<<dim3(NR / 4), b256, 0, stream>>>(src, sel, s2_bf, g1, be1, x_bf);
  // h = relu(x @ W1^T + b1)  (bf16, N=1024)
  gemm64<1><<<dim3(16, MT), b256, 0, stream>>>(
      x_bf, 256, WB + WOF_1, 256, b1, 256, h_bf, nullptr, 1024);
  // y = h @ W2^T + b2  (bf16, K=1024)
  gemm64<0><<<dim3(4, MT), b256, 0, stream>>>(
      h_bf, 1024, WB + WOF_2, 1024, b2, 1024, y_bf, nullptr, 256);
  // out = LN(x + y) scattered
  ln2_k<<<dim3(NR / 4), b256, 0, stream>>>(x_bf, y_bf, g2, be2, (float*)d_out);
  // all_vt pass-through
  hipMemcpyAsync((float*)d_out + OUT0, all_vt, OUT1 * sizeof(float),
                 hipMemcpyDeviceToDevice, stream);
}